// Round 17
// baseline (216.385 us; speedup 1.0000x reference)
//
#include <hip/hip_runtime.h>

// head u32 words: 0:c0 1:c123 | hf[6]=shi_msg hf[7]=slo_msg hf[8]=shi_out hf[9]=slo_out
//                 11: nB (count of d>16 nodes, filled by finesort)
// 10-launch pipeline: zero -> detect -> MEGA(histM || rowmax_canon) -> colscan
//   -> binplace (inline btot-scan bases) -> scales(msg) ->
//   MEGA(finesort || quant8) -> MEGA(aggr_small || grid-stride aggr_wave) ->
//   scales(out) -> quant_rows.
// FULL (mode 2): u64 payload (local<<56)|(src<<32)|(msk<<24)|e ; int8 rows xq8.
// COMPAT (mode 1): u32 payloads, aggr gathers src/msk. RAW (mode 0): quant on the fly.
// rowmax[] carries msk in its sign bit. Constraints: E < 2^24, N < 2^24, bsh <= 8.

#define FS_CAP 2560
#define WAVE_BLOCKS 1024

__global__ void k_zero(unsigned* p, int n) {
  int i = blockIdx.x * blockDim.x + threadIdx.x;
  for (; i < n; i += gridDim.x * blockDim.x) p[i] = 0u;
}

// Sniff mask dtype from raw bytes (reads only N bytes, safe for u8/i32/f32).
__global__ void k_detect(const unsigned char* m, unsigned* head, int nbytes) {
  int i = blockIdx.x * blockDim.x + threadIdx.x;
  int c0 = 0, c123 = 0;
  for (; i < nbytes; i += gridDim.x * blockDim.x) {
    unsigned char b = m[i];
    if (b) { if ((i & 3) == 0) c0++; else c123++; }
  }
  for (int o = 32; o; o >>= 1) { c0 += __shfl_xor(c0, o); c123 += __shfl_xor(c123, o); }
  if ((threadIdx.x & 63) == 0) {
    if (c0)   atomicAdd(&head[0], (unsigned)c0);
    if (c123) atomicAdd(&head[1], (unsigned)c123);
  }
}

__device__ __forceinline__ unsigned char mask_of(const void* mraw, unsigned c0,
                                                 unsigned c123, int i) {
  int mode = (c123 == 0u) ? 1 : ((c0 == 0u) ? 2 : 0);
  if (mode == 0)      return ((const unsigned char*)mraw)[i] != 0;
  else if (mode == 1) return ((const int*)mraw)[i] != 0;
  else                return ((const float*)mraw)[i] != 0.0f;
}

// MEGA: blocks [0,nbp) = per-chunk LDS histogram of dst>>bsh -> M[chunk][NB];
//       blocks [nbp,..) = mask canon + rowmax (msk in sign bit).
__global__ void k_mega_hr(const int* dst, unsigned* M, int E, int NB, int bsh,
                          int vec, int bpchunk, int nbp,
                          const float* x, const void* mraw, const unsigned* head,
                          float* rowmax, unsigned char* msk, int N) {
  __shared__ unsigned h[1024];
  if ((int)blockIdx.x < nbp) {
    int chunk = blockIdx.x;
    int cbase = chunk * bpchunk;
    int cend = cbase + bpchunk; if (cend > E) cend = E;
    int n = cend - cbase;
    int n4 = vec ? (n >> 2) : 0;
    for (int i = threadIdx.x; i < NB; i += 256) h[i] = 0u;
    __syncthreads();
    const int4* d4 = (const int4*)(dst + cbase);
    for (int i = threadIdx.x; i < n4; i += 256) {
      int4 v = d4[i];
      atomicAdd(&h[((unsigned)v.x) >> bsh], 1u);
      atomicAdd(&h[((unsigned)v.y) >> bsh], 1u);
      atomicAdd(&h[((unsigned)v.z) >> bsh], 1u);
      atomicAdd(&h[((unsigned)v.w) >> bsh], 1u);
    }
    for (int e = cbase + n4 * 4 + threadIdx.x; e < cend; e += 256)
      atomicAdd(&h[((unsigned)dst[e]) >> bsh], 1u);
    __syncthreads();
    for (int i = threadIdx.x; i < NB; i += 256)
      M[(size_t)chunk * NB + i] = h[i];
  } else {
    int bid = blockIdx.x - nbp;
    unsigned c0 = head[0], c123 = head[1];
    int gid = bid * 256 + threadIdx.x;
    if (gid < N) msk[gid] = mask_of(mraw, c0, c123, gid);
    int w = gid >> 6;
    int lane = threadIdx.x & 63;
    if (w >= N) return;
    float v = fabsf(x[(size_t)w * 64 + lane]);
    for (int o = 32; o; o >>= 1) v = fmaxf(v, __shfl_xor(v, o));
    if (lane == 0) {
      unsigned char m = mask_of(mraw, c0, c123, w);
      rowmax[w] = m ? -v : v;   // sign bit = mask class (v==0 -> -0.0f keeps bit)
    }
  }
}

// One wave per bucket: exclusive prefix of M[*][b] over chunks; total -> btot[b].
__global__ void k_colscan(unsigned* M, unsigned* btot, int nbp, int NB) {
  int b = blockIdx.x;
  if (b >= NB) return;
  int lane = threadIdx.x & 63;
  unsigned run = 0;
  for (int c0 = 0; c0 < nbp; c0 += 64) {
    int c = c0 + lane;
    unsigned orig = (c < nbp) ? M[(size_t)c * NB + b] : 0u;
    unsigned v = orig;
    #pragma unroll
    for (int o = 1; o < 64; o <<= 1) {
      unsigned u = __shfl_up(v, o);
      if (lane >= o) v += u;
    }
    if (c < nbp) M[(size_t)c * NB + b] = run + v - orig;
    run += __shfl(v, 63);
  }
  if (lane == 0) btot[b] = run;
}

// Coarse binning with deterministic bases (base = scan(btot) + M prefix), scan
// computed inline in LDS. One gather per edge: rowmax[src] for class amax.
__global__ void k_binplace(const int* src, const int* dst, const float* rowmax,
                           const unsigned* M, const unsigned* btot,
                           unsigned long long* cbuf64, unsigned* cbuf32,
                           unsigned* slot_ehi, unsigned* slot_elo,
                           int E, int NB, int bsh, int full, int vec, int bpchunk) {
  __shared__ unsigned h[1024], base[1024];
  __shared__ float sh_hi[4], sh_lo[4];
  int t = threadIdx.x;
  int chunk = blockIdx.x;
  for (int i = t; i < 1024; i += 256) base[i] = (i < NB) ? btot[i] : 0u;
  __syncthreads();
  for (int off = 1; off < 1024; off <<= 1) {
    unsigned v[4];
    #pragma unroll
    for (int j = 0; j < 4; j++) { int i = t + j * 256; v[j] = (i >= off) ? base[i - off] : 0u; }
    __syncthreads();
    #pragma unroll
    for (int j = 0; j < 4; j++) { int i = t + j * 256; base[i] += v[j]; }
    __syncthreads();
  }
  unsigned tmpv[4];
  #pragma unroll
  for (int j = 0; j < 4; j++) { int i = t + j * 256; tmpv[j] = (i == 0) ? 0u : base[i - 1]; }
  __syncthreads();
  #pragma unroll
  for (int j = 0; j < 4; j++) {
    int i = t + j * 256;
    h[i] = 0u;
    if (i < NB) base[i] = tmpv[j] + M[(size_t)chunk * NB + i];
  }
  __syncthreads();
  int cbase = chunk * bpchunk;
  int cend = cbase + bpchunk; if (cend > E) cend = E;
  int n = cend - cbase;
  int n4 = vec ? (n >> 2) : 0;
  unsigned lmask = (1u << bsh) - 1u;
  float hi = 0.0f, lo = 0.0f;
  const int4* d4 = (const int4*)(dst + cbase);
  const int4* s4 = (const int4*)(src + cbase);
  for (int i = threadIdx.x; i < n4; i += 256) {
    int4 dv = d4[i]; int4 sv = s4[i];
    int e0 = cbase + i * 4;
    int dd[4] = {dv.x, dv.y, dv.z, dv.w};
    int ss[4] = {sv.x, sv.y, sv.z, sv.w};
    #pragma unroll
    for (int j = 0; j < 4; j++) {
      int d = dd[j], s = ss[j];
      float r = rowmax[s];
      unsigned mk = (__float_as_uint(r) >> 31);
      float av = fabsf(r);
      if (mk) hi = fmaxf(hi, av); else lo = fmaxf(lo, av);
      unsigned b = (unsigned)d >> bsh;
      unsigned pos = base[b] + atomicAdd(&h[b], 1u);
      if (full)
        cbuf64[pos] = ((unsigned long long)(((((unsigned)d) & lmask) << 24) | (unsigned)s) << 32)
                      | ((mk << 24) | (unsigned)(e0 + j));
      else
        cbuf32[pos] = ((((unsigned)d) & lmask) << 24) | (unsigned)(e0 + j);
    }
  }
  for (int e = cbase + n4 * 4 + threadIdx.x; e < cend; e += 256) {
    int d = dst[e], s = src[e];
    float r = rowmax[s];
    unsigned mk = (__float_as_uint(r) >> 31);
    float av = fabsf(r);
    if (mk) hi = fmaxf(hi, av); else lo = fmaxf(lo, av);
    unsigned b = (unsigned)d >> bsh;
    unsigned pos = base[b] + atomicAdd(&h[b], 1u);
    if (full)
      cbuf64[pos] = ((unsigned long long)(((((unsigned)d) & lmask) << 24) | (unsigned)s) << 32)
                    | ((mk << 24) | (unsigned)e);
    else
      cbuf32[pos] = ((((unsigned)d) & lmask) << 24) | (unsigned)e;
  }
  for (int o = 32; o; o >>= 1) { hi = fmaxf(hi, __shfl_xor(hi, o)); lo = fmaxf(lo, __shfl_xor(lo, o)); }
  int wid = threadIdx.x >> 6, lane = threadIdx.x & 63;
  if (lane == 0) { sh_hi[wid] = hi; sh_lo[wid] = lo; }
  __syncthreads();
  if (threadIdx.x == 0) {
    float hh = fmaxf(fmaxf(sh_hi[0], sh_hi[1]), fmaxf(sh_hi[2], sh_hi[3]));
    float ll = fmaxf(fmaxf(sh_lo[0], sh_lo[1]), fmaxf(sh_lo[2], sh_lo[3]));
    atomicMax(&slot_ehi[blockIdx.x & 255], __float_as_uint(hh));
    atomicMax(&slot_elo[blockIdx.x & 255], __float_as_uint(ll));
  }
}

// Reduce 256-slot amax arrays -> scales in head. which=0: msg; which=1: out.
__global__ void k_scales(unsigned* head, const unsigned* shi, const unsigned* slo, int which) {
  __shared__ unsigned smh[256], sml[256];
  int t = threadIdx.x;
  smh[t] = shi[t]; sml[t] = slo[t];
  __syncthreads();
  for (int off = 128; off > 0; off >>= 1) {
    if (t < off) {
      smh[t] = smh[t] > smh[t + off] ? smh[t] : smh[t + off];
      sml[t] = sml[t] > sml[t + off] ? sml[t] : sml[t + off];
    }
    __syncthreads();
  }
  if (t == 0) {
    float* hf = (float*)head;
    float ah = __uint_as_float(smh[0]);
    float al = __uint_as_float(sml[0]);
    hf[6 + which * 2]     = __fdiv_rn(fmaxf(ah, 1e-8f), 127.0f);
    hf[6 + which * 2 + 1] = __fdiv_rn(fmaxf(al, 1e-8f), 7.0f);
  }
}

// MEGA: blocks [0,NB) = finesort; blocks [NB,..) = quant8.
__global__ void k_mega_fq(const unsigned long long* cbuf64, const unsigned* cbuf32,
                          const unsigned* btot,
                          unsigned long long* opay, unsigned* order32,
                          unsigned long long* meta, unsigned* head,
                          unsigned* nodeB, int N, int NB, int bsh, int full,
                          const float* x, signed char* xq8, const unsigned char* msk) {
  __shared__ unsigned h[256], lofs[256], cur[256];
  __shared__ unsigned sb[1024];
  __shared__ unsigned long long srt[FS_CAP];
  __shared__ unsigned bigcnt, bigbase;
  int t = threadIdx.x;
  if ((int)blockIdx.x >= NB) {
    int bid = blockIdx.x - NB;
    int w = (bid * 256 + t) >> 6;
    int lane = t & 63;
    if (w >= N) return;
    const float* hf = (const float*)head;
    bool m = msk[w] != 0;
    float sc = m ? hf[6] : hf[7];
    float qm = m ? 127.0f : 7.0f;
    float tv = __fdiv_rn(x[(size_t)w * 64 + lane], sc);
    tv = fminf(fmaxf(tv, -qm), qm);
    tv = rintf(tv);
    xq8[(size_t)w * 64 + lane] = (signed char)tv;
    return;
  }
  int b = blockIdx.x;
  for (int i = t; i < 1024; i += 256) sb[i] = (i < NB) ? btot[i] : 0u;
  __syncthreads();
  for (int off = 1; off < 1024; off <<= 1) {
    unsigned v[4];
    #pragma unroll
    for (int j = 0; j < 4; j++) { int i = t + j * 256; v[j] = (i >= off) ? sb[i - off] : 0u; }
    __syncthreads();
    #pragma unroll
    for (int j = 0; j < 4; j++) { int i = t + j * 256; sb[i] += v[j]; }
    __syncthreads();
  }
  unsigned rbase = (b == 0) ? 0u : sb[b - 1];
  unsigned rend = sb[b];
  unsigned n = rend - rbase;
  h[t] = 0u;
  if (t == 0) bigcnt = 0u;
  __syncthreads();
  bool staged = (n <= (unsigned)FS_CAP);
  for (unsigned j = rbase + (unsigned)t; j < rend; j += 256) {
    unsigned loc = full ? (unsigned)(cbuf64[j] >> 56) : (cbuf32[j] >> 24);
    atomicAdd(&h[loc], 1u);
  }
  __syncthreads();
  lofs[t] = h[t];
  __syncthreads();
  for (int off = 1; off < 256; off <<= 1) {
    unsigned v = (t >= off) ? lofs[t - off] : 0u;
    __syncthreads();
    lofs[t] += v;
    __syncthreads();
  }
  unsigned dcount = h[t];
  unsigned excl = lofs[t] - dcount;
  cur[t] = excl;
  int nper = 1 << bsh;
  int node = (b << bsh) + t;
  bool valid = (t < nper) && (node < N);
  if (valid)
    meta[node] = ((unsigned long long)dcount << 32) | (unsigned long long)(rbase + excl);
  unsigned myidx = 0u;
  bool big = valid && dcount > 16u;
  if (big) myidx = atomicAdd(&bigcnt, 1u);
  __syncthreads();
  if (t == 0 && bigcnt) bigbase = atomicAdd(&head[11], bigcnt);
  __syncthreads();
  if (big) nodeB[bigbase + myidx] = (unsigned)node;
  if (staged) {
    for (unsigned j = (unsigned)t; j < n; j += 256) {
      unsigned long long v = full ? cbuf64[rbase + j]
                                  : (unsigned long long)cbuf32[rbase + j];
      unsigned loc = full ? (unsigned)(v >> 56) : (((unsigned)v) >> 24);
      srt[atomicAdd(&cur[loc], 1u)] = v;
    }
    __syncthreads();
    if (valid && dcount > 1u) {
      for (unsigned i = 1; i < dcount; i++) {
        unsigned long long key = srt[excl + i];
        unsigned kk = (unsigned)key & 0xFFFFFFu;
        int j = (int)i - 1;
        while (j >= 0 && ((unsigned)srt[excl + j] & 0xFFFFFFu) > kk) {
          srt[excl + j + 1] = srt[excl + j]; j--;
        }
        srt[excl + (unsigned)(j + 1)] = key;
      }
    }
    __syncthreads();
    for (unsigned j = (unsigned)t; j < n; j += 256) {
      if (full) opay[rbase + j] = srt[j];
      else order32[rbase + j] = (unsigned)srt[j] & 0x00FFFFFFu;
    }
  } else {
    for (unsigned j = rbase + (unsigned)t; j < rend; j += 256) {
      if (full) {
        unsigned long long v = cbuf64[j];
        unsigned pos = rbase + atomicAdd(&cur[(unsigned)(v >> 56)], 1u);
        opay[pos] = v;
      } else {
        unsigned v = cbuf32[j];
        unsigned pos = rbase + atomicAdd(&cur[v >> 24], 1u);
        order32[pos] = v & 0x00FFFFFFu;
      }
    }
    __syncthreads();
    if (valid && dcount > 1u) {
      unsigned s0 = rbase + excl;
      if (full) {
        for (unsigned i = 1; i < dcount; i++) {
          unsigned long long key = opay[s0 + i];
          unsigned kk = (unsigned)key & 0xFFFFFFu;
          int j = (int)i - 1;
          while (j >= 0 && ((unsigned)opay[s0 + j] & 0xFFFFFFu) > kk) {
            opay[s0 + j + 1] = opay[s0 + j]; j--;
          }
          opay[s0 + (unsigned)(j + 1)] = key;
        }
      } else {
        for (unsigned i = 1; i < dcount; i++) {
          unsigned key = order32[s0 + i];
          int j = (int)i - 1;
          while (j >= 0 && order32[s0 + j] > key) { order32[s0 + j + 1] = order32[s0 + j]; j--; }
          order32[s0 + (unsigned)(j + 1)] = key;
        }
      }
    }
  }
}

// MEGA: blocks [0,smallBlocks) = small nodes (d<=16); blocks
// [smallBlocks, smallBlocks+WAVE_BLOCKS) = GRID-STRIDE wave-per-node over the
// big-node list (or all nodes in mode0).
__global__ void k_mega_aggr(const signed char* xq8, const float* x,
                            const unsigned long long* opay, const unsigned* order32,
                            const int* src, const unsigned char* msk,
                            const unsigned long long* meta, const unsigned* head,
                            const unsigned* nodeB,
                            unsigned* slot_ohi, unsigned* slot_olo,
                            float* out, int N, int mode, int smallBlocks, int use_list) {
  const float* hf = (const float*)head;
  float shi = hf[6], slo = hf[7];
  if ((int)blockIdx.x < smallBlocks) {
    int t = blockIdx.x * 256 + threadIdx.x;
    int node = t >> 4;
    int g = threadIdx.x & 15;
    if (node >= N) return;
    unsigned long long mm = meta[node];
    unsigned d = (unsigned)(mm >> 32);
    if (d > 16u) return;
    unsigned s0 = (unsigned)mm;
    unsigned pay = 0u;
    if ((unsigned)g < d) {
      if (mode == 2) {
        unsigned long long v = opay[s0 + (unsigned)g];
        pay = ((unsigned)(v >> 32) & 0xFFFFFFu) | (((unsigned)(v >> 24) & 1u) << 31);
      } else {
        unsigned e = order32[s0 + (unsigned)g];
        int s = src[e];
        pay = (unsigned)s | (((unsigned)msk[s]) << 31);
      }
    }
    int gbase = threadIdx.x & ~15;
    unsigned wv[16];
    #pragma unroll
    for (int j = 0; j < 16; j++) {
      int sl = gbase + ((j < (int)d) ? j : 0);
      unsigned p = __shfl(pay, sl);
      wv[j] = *(const unsigned*)(xq8 + (size_t)(p & 0x7FFFFFFFu) * 64 + g * 4);
    }
    float acc0 = 0.0f, acc1 = 0.0f, acc2 = 0.0f, acc3 = 0.0f;
    #pragma unroll
    for (int j = 0; j < 16; j++) {
      int sl = gbase + ((j < (int)d) ? j : 0);
      unsigned p = __shfl(pay, sl);
      float s = (j < (int)d) ? ((p >> 31) ? shi : slo) : 0.0f;  // 0-scale pads: +-0
      unsigned w = wv[j];
      acc0 = __fadd_rn(acc0, __fmul_rn(s, (float)(int)(signed char)(w & 0xFF)));
      acc1 = __fadd_rn(acc1, __fmul_rn(s, (float)(int)(signed char)((w >> 8) & 0xFF)));
      acc2 = __fadd_rn(acc2, __fmul_rn(s, (float)(int)(signed char)((w >> 16) & 0xFF)));
      acc3 = __fadd_rn(acc3, __fmul_rn(s, (float)(int)(signed char)((w >> 24) & 0xFF)));
    }
    float4 o4; o4.x = acc0; o4.y = acc1; o4.z = acc2; o4.w = acc3;
    *(float4*)(out + (size_t)node * 64 + g * 4) = o4;
    float a = fmaxf(fmaxf(fabsf(acc0), fabsf(acc1)), fmaxf(fabsf(acc2), fabsf(acc3)));
    #pragma unroll
    for (int o = 8; o; o >>= 1) a = fmaxf(a, __shfl_xor(a, o));
    if (g == 0) {
      unsigned* sl = msk[node] ? slot_ohi : slot_olo;
      atomicMax(&sl[node & 255], __float_as_uint(a));
    }
    return;
  }
  // ---- grid-stride wave-per-node phase ----
  int bid = blockIdx.x - smallBlocks;
  int lane = threadIdx.x & 63;
  int wid = threadIdx.x >> 6;
  unsigned limit = use_list ? head[11] : (unsigned)N;
  unsigned stride = (unsigned)WAVE_BLOCKS * 4u;
  for (unsigned w = (unsigned)bid * 4u + (unsigned)wid; w < limit; w += stride) {
    int node = use_list ? (int)nodeB[w] : (int)w;
    unsigned long long mm = meta[node];
    unsigned d = (unsigned)(mm >> 32);
    unsigned s0 = (unsigned)mm;
    float acc = 0.0f;
    if (d <= 64u) {
      unsigned pay = 0u;
      if ((unsigned)lane < d) {
        if (mode == 2) {
          unsigned long long v = opay[s0 + (unsigned)lane];
          pay = ((unsigned)(v >> 32) & 0xFFFFFFu) | (((unsigned)(v >> 24) & 1u) << 31);
        } else {
          unsigned e = order32[s0 + (unsigned)lane];
          int s = src[e];
          pay = (unsigned)s | (((unsigned)msk[s]) << 31);
        }
      }
      for (unsigned kb = 0; kb < d; kb += 16) {
        float vv[16];
        #pragma unroll
        for (int j = 0; j < 16; j++) {
          unsigned kk = kb + (unsigned)j;
          int sl = (int)(kk < d ? kk : 0u);
          unsigned p = __shfl(pay, sl);
          float sc = (p >> 31) ? shi : slo;
          float scm = (kk < d) ? sc : 0.0f;
          unsigned sn = p & 0x7FFFFFFFu;
          float q;
          if (mode >= 1) {
            q = (float)xq8[(size_t)sn * 64 + lane];
          } else {
            float qm = (p >> 31) ? 127.0f : 7.0f;
            float tq = __fdiv_rn(x[(size_t)sn * 64 + lane], sc);
            tq = fminf(fmaxf(tq, -qm), qm);
            q = rintf(tq);
          }
          vv[j] = __fmul_rn(scm, q);
        }
        #pragma unroll
        for (int j = 0; j < 16; j++) acc = __fadd_rn(acc, vv[j]);
      }
    } else {
      for (unsigned k = 0; k < d; k++) {
        unsigned sn; bool m;
        if (mode == 2) {
          unsigned long long v = opay[s0 + k];
          sn = (unsigned)(v >> 32) & 0xFFFFFFu;
          m = ((v >> 24) & 1ull) != 0;
        } else {
          unsigned e = order32[s0 + k];
          sn = (unsigned)src[e];
          m = msk[sn] != 0;
        }
        float sc = m ? shi : slo;
        float q;
        if (mode >= 1) {
          q = (float)xq8[(size_t)sn * 64 + lane];
        } else {
          float qm = m ? 127.0f : 7.0f;
          float tq = __fdiv_rn(x[(size_t)sn * 64 + lane], sc);
          tq = fminf(fmaxf(tq, -qm), qm);
          q = rintf(tq);
        }
        acc = __fadd_rn(acc, __fmul_rn(sc, q));
      }
    }
    out[(size_t)node * 64 + lane] = acc;
    float a = fabsf(acc);
    for (int o = 32; o; o >>= 1) a = fmaxf(a, __shfl_xor(a, o));
    if (lane == 0) {
      unsigned* sl = (msk[node] != 0) ? slot_ohi : slot_olo;
      atomicMax(&sl[node & 255], __float_as_uint(a));
    }
  }
}

// Final fake-quant of output rows (in-place, float).
__global__ void k_quant_rows(const float* in, float* out, const unsigned char* msk,
                             const unsigned* head, int N) {
  int w = (int)((blockIdx.x * blockDim.x + threadIdx.x) >> 6);
  int lane = threadIdx.x & 63;
  if (w >= N) return;
  const float* hf = (const float*)head;
  bool m = msk[w] != 0;
  float sc = m ? hf[8] : hf[9];
  float qm = m ? 127.0f : 7.0f;
  float v = in[(size_t)w * 64 + lane];
  float t = __fdiv_rn(v, sc);
  t = fminf(fmaxf(t, -qm), qm);
  t = rintf(t);
  out[(size_t)w * 64 + lane] = __fmul_rn(sc, t);
}

extern "C" void kernel_launch(void* const* d_in, const int* in_sizes, int n_in,
                              void* d_out, int out_size, void* d_ws, size_t ws_size,
                              hipStream_t stream) {
  const float* x = (const float*)d_in[0];
  const int* ei = (const int*)d_in[1];
  const void* mraw = d_in[2];
  int N = in_sizes[2];
  int E = in_sizes[1] / 2;
  const int* src = ei;
  const int* dst = ei + E;
  float* out = (float*)d_out;

  int bsh = 7;
  while ((((N - 1) >> bsh) + 1) > 1024 && bsh < 8) bsh++;
  int NB = ((N - 1) >> bsh) + 1;
  int vec = (((uintptr_t)src & 15) == 0) && (((uintptr_t)dst & 15) == 0);

  int bpchunk = 2048;
  if ((E + bpchunk - 1) / bpchunk > 512)
    bpchunk = (((E + 511) / 512) + 3) & ~3;
  int nbp = (E + bpchunk - 1) / bpchunk;

  char* ws = (char*)d_ws;
  auto al = [](size_t v) { return ((v + 255) / 256) * 256; };
  size_t o_sehi = 256, o_selo = 1280, o_sohi = 2304, o_solo = 3328;
  size_t o_btot = 4352;
  size_t o_M = al(o_btot + (size_t)(NB + 1) * 4);
  size_t o_msk = al(o_M + (size_t)nbp * NB * 4);
  size_t o_rowmax = al(o_msk + (size_t)N);
  size_t o_meta = al(o_rowmax + (size_t)N * 4);
  size_t o_nodeB = o_meta + (size_t)N * 8;
  size_t o_cbuf = al(o_nodeB + (size_t)N * 4);

  size_t o_opay = al(o_cbuf + (size_t)E * 8);
  size_t o_xq8f = al(o_opay + (size_t)E * 8);
  size_t need_full = o_xq8f + (size_t)N * 64;
  size_t o_order_c = al(o_cbuf + (size_t)E * 4);
  size_t o_xq8c = al(o_order_c + (size_t)E * 4);
  size_t need_compat = o_xq8c + (size_t)N * 64;

  int mode;
  if (ws_size >= need_full && E < (1 << 24) && N < (1 << 24)) mode = 2;
  else if (ws_size >= need_compat && E < (1 << 24)) mode = 1;
  else mode = 0;

  unsigned* head = (unsigned*)ws;
  unsigned* slot_ehi = (unsigned*)(ws + o_sehi);
  unsigned* slot_elo = (unsigned*)(ws + o_selo);
  unsigned* slot_ohi = (unsigned*)(ws + o_sohi);
  unsigned* slot_olo = (unsigned*)(ws + o_solo);
  unsigned* btot = (unsigned*)(ws + o_btot);
  unsigned* M = (unsigned*)(ws + o_M);
  unsigned char* msk = (unsigned char*)(ws + o_msk);
  float* rowmax = (float*)(ws + o_rowmax);
  unsigned long long* meta = (unsigned long long*)(ws + o_meta);
  unsigned* nodeB = (unsigned*)(ws + o_nodeB);
  unsigned long long* cbuf64 = (unsigned long long*)(ws + o_cbuf);
  unsigned* cbuf32 = (unsigned*)(ws + o_cbuf);
  unsigned long long* opay = (unsigned long long*)(ws + o_opay);
  unsigned* order32 = (unsigned*)(ws + o_order_c);
  signed char* xq8 = (signed char*)(ws + ((mode == 2) ? o_xq8f : o_xq8c));

  int rowBlocks = (N + 3) / 4;
  int full = (mode == 2);
  int smallBlocks = (mode >= 1) ? (N + 15) / 16 : 0;
  int qBlocks = (mode >= 1) ? rowBlocks : 0;

  k_zero<<<8, 256, 0, stream>>>(head, 1088);   // head + 4 slot arrays
  k_detect<<<256, 256, 0, stream>>>((const unsigned char*)mraw, head, N);
  k_mega_hr<<<nbp + rowBlocks, 256, 0, stream>>>(dst, M, E, NB, bsh, vec, bpchunk, nbp,
                                                 x, mraw, head, rowmax, msk, N);
  k_colscan<<<NB, 64, 0, stream>>>(M, btot, nbp, NB);
  k_binplace<<<nbp, 256, 0, stream>>>(src, dst, rowmax, M, btot, cbuf64, cbuf32,
                                      slot_ehi, slot_elo, E, NB, bsh, full, vec, bpchunk);
  k_scales<<<1, 256, 0, stream>>>(head, slot_ehi, slot_elo, 0);
  k_mega_fq<<<NB + qBlocks, 256, 0, stream>>>(cbuf64, cbuf32, btot, opay, order32,
                                              meta, head, nodeB, N, NB, bsh, full,
                                              x, xq8, msk);
  k_mega_aggr<<<smallBlocks + WAVE_BLOCKS, 256, 0, stream>>>(xq8, x, opay, order32,
                                                             src, msk, meta, head, nodeB,
                                                             slot_ohi, slot_olo, out, N,
                                                             mode, smallBlocks,
                                                             (mode >= 1) ? 1 : 0);
  k_scales<<<1, 256, 0, stream>>>(head, slot_ohi, slot_olo, 1);
  k_quant_rows<<<rowBlocks, 256, 0, stream>>>(out, out, msk, head, N);
}

// Round 18
// 155.714 us; speedup vs baseline: 1.3896x; 1.3896x over previous
//
#include <hip/hip_runtime.h>

// head u32 words: 0:c0 1:c123 | hf[6]=shi_msg hf[7]=slo_msg hf[8]=shi_out hf[9]=slo_out
// 10-launch pipeline: zero -> detect -> MEGA(histM || rowmax_canon) -> colscan
//   -> binplace (inline btot-scan bases) -> scales(msg) ->
//   MEGA(finesort || quant8) -> aggr_uni (16-lane group per node, ANY degree)
//   -> scales(out) -> quant_rows.
// FULL (mode 2): u64 payload (local<<56)|(src<<32)|(msk<<24)|e ; int8 rows xq8.
// COMPAT (mode 1): u32 payloads, aggr gathers src/msk. RAW (mode 0): quant on the fly.
// rowmax[] carries msk in its sign bit. Constraints: E < 2^24, N < 2^24, bsh <= 8.

#define FS_CAP 2560

__global__ void k_zero(unsigned* p, int n) {
  int i = blockIdx.x * blockDim.x + threadIdx.x;
  for (; i < n; i += gridDim.x * blockDim.x) p[i] = 0u;
}

// Sniff mask dtype from raw bytes (reads only N bytes, safe for u8/i32/f32).
__global__ void k_detect(const unsigned char* m, unsigned* head, int nbytes) {
  int i = blockIdx.x * blockDim.x + threadIdx.x;
  int c0 = 0, c123 = 0;
  for (; i < nbytes; i += gridDim.x * blockDim.x) {
    unsigned char b = m[i];
    if (b) { if ((i & 3) == 0) c0++; else c123++; }
  }
  for (int o = 32; o; o >>= 1) { c0 += __shfl_xor(c0, o); c123 += __shfl_xor(c123, o); }
  if ((threadIdx.x & 63) == 0) {
    if (c0)   atomicAdd(&head[0], (unsigned)c0);
    if (c123) atomicAdd(&head[1], (unsigned)c123);
  }
}

__device__ __forceinline__ unsigned char mask_of(const void* mraw, unsigned c0,
                                                 unsigned c123, int i) {
  int mode = (c123 == 0u) ? 1 : ((c0 == 0u) ? 2 : 0);
  if (mode == 0)      return ((const unsigned char*)mraw)[i] != 0;
  else if (mode == 1) return ((const int*)mraw)[i] != 0;
  else                return ((const float*)mraw)[i] != 0.0f;
}

// MEGA: blocks [0,nbp) = per-chunk LDS histogram of dst>>bsh -> M[chunk][NB];
//       blocks [nbp,..) = mask canon + rowmax (msk in sign bit).
__global__ void k_mega_hr(const int* dst, unsigned* M, int E, int NB, int bsh,
                          int vec, int bpchunk, int nbp,
                          const float* x, const void* mraw, const unsigned* head,
                          float* rowmax, unsigned char* msk, int N) {
  __shared__ unsigned h[1024];
  if ((int)blockIdx.x < nbp) {
    int chunk = blockIdx.x;
    int cbase = chunk * bpchunk;
    int cend = cbase + bpchunk; if (cend > E) cend = E;
    int n = cend - cbase;
    int n4 = vec ? (n >> 2) : 0;
    for (int i = threadIdx.x; i < NB; i += 256) h[i] = 0u;
    __syncthreads();
    const int4* d4 = (const int4*)(dst + cbase);
    for (int i = threadIdx.x; i < n4; i += 256) {
      int4 v = d4[i];
      atomicAdd(&h[((unsigned)v.x) >> bsh], 1u);
      atomicAdd(&h[((unsigned)v.y) >> bsh], 1u);
      atomicAdd(&h[((unsigned)v.z) >> bsh], 1u);
      atomicAdd(&h[((unsigned)v.w) >> bsh], 1u);
    }
    for (int e = cbase + n4 * 4 + threadIdx.x; e < cend; e += 256)
      atomicAdd(&h[((unsigned)dst[e]) >> bsh], 1u);
    __syncthreads();
    for (int i = threadIdx.x; i < NB; i += 256)
      M[(size_t)chunk * NB + i] = h[i];
  } else {
    int bid = blockIdx.x - nbp;
    unsigned c0 = head[0], c123 = head[1];
    int gid = bid * 256 + threadIdx.x;
    if (gid < N) msk[gid] = mask_of(mraw, c0, c123, gid);
    int w = gid >> 6;
    int lane = threadIdx.x & 63;
    if (w >= N) return;
    float v = fabsf(x[(size_t)w * 64 + lane]);
    for (int o = 32; o; o >>= 1) v = fmaxf(v, __shfl_xor(v, o));
    if (lane == 0) {
      unsigned char m = mask_of(mraw, c0, c123, w);
      rowmax[w] = m ? -v : v;   // sign bit = mask class (v==0 -> -0.0f keeps bit)
    }
  }
}

// One wave per bucket: exclusive prefix of M[*][b] over chunks; total -> btot[b].
__global__ void k_colscan(unsigned* M, unsigned* btot, int nbp, int NB) {
  int b = blockIdx.x;
  if (b >= NB) return;
  int lane = threadIdx.x & 63;
  unsigned run = 0;
  for (int c0 = 0; c0 < nbp; c0 += 64) {
    int c = c0 + lane;
    unsigned orig = (c < nbp) ? M[(size_t)c * NB + b] : 0u;
    unsigned v = orig;
    #pragma unroll
    for (int o = 1; o < 64; o <<= 1) {
      unsigned u = __shfl_up(v, o);
      if (lane >= o) v += u;
    }
    if (c < nbp) M[(size_t)c * NB + b] = run + v - orig;
    run += __shfl(v, 63);
  }
  if (lane == 0) btot[b] = run;
}

// Coarse binning with deterministic bases (base = scan(btot) + M prefix), scan
// computed inline in LDS. One gather per edge: rowmax[src] for class amax.
__global__ void k_binplace(const int* src, const int* dst, const float* rowmax,
                           const unsigned* M, const unsigned* btot,
                           unsigned long long* cbuf64, unsigned* cbuf32,
                           unsigned* slot_ehi, unsigned* slot_elo,
                           int E, int NB, int bsh, int full, int vec, int bpchunk) {
  __shared__ unsigned h[1024], base[1024];
  __shared__ float sh_hi[4], sh_lo[4];
  int t = threadIdx.x;
  int chunk = blockIdx.x;
  for (int i = t; i < 1024; i += 256) base[i] = (i < NB) ? btot[i] : 0u;
  __syncthreads();
  for (int off = 1; off < 1024; off <<= 1) {
    unsigned v[4];
    #pragma unroll
    for (int j = 0; j < 4; j++) { int i = t + j * 256; v[j] = (i >= off) ? base[i - off] : 0u; }
    __syncthreads();
    #pragma unroll
    for (int j = 0; j < 4; j++) { int i = t + j * 256; base[i] += v[j]; }
    __syncthreads();
  }
  unsigned tmpv[4];
  #pragma unroll
  for (int j = 0; j < 4; j++) { int i = t + j * 256; tmpv[j] = (i == 0) ? 0u : base[i - 1]; }
  __syncthreads();
  #pragma unroll
  for (int j = 0; j < 4; j++) {
    int i = t + j * 256;
    h[i] = 0u;
    if (i < NB) base[i] = tmpv[j] + M[(size_t)chunk * NB + i];
  }
  __syncthreads();
  int cbase = chunk * bpchunk;
  int cend = cbase + bpchunk; if (cend > E) cend = E;
  int n = cend - cbase;
  int n4 = vec ? (n >> 2) : 0;
  unsigned lmask = (1u << bsh) - 1u;
  float hi = 0.0f, lo = 0.0f;
  const int4* d4 = (const int4*)(dst + cbase);
  const int4* s4 = (const int4*)(src + cbase);
  for (int i = threadIdx.x; i < n4; i += 256) {
    int4 dv = d4[i]; int4 sv = s4[i];
    int e0 = cbase + i * 4;
    int dd[4] = {dv.x, dv.y, dv.z, dv.w};
    int ss[4] = {sv.x, sv.y, sv.z, sv.w};
    #pragma unroll
    for (int j = 0; j < 4; j++) {
      int d = dd[j], s = ss[j];
      float r = rowmax[s];
      unsigned mk = (__float_as_uint(r) >> 31);
      float av = fabsf(r);
      if (mk) hi = fmaxf(hi, av); else lo = fmaxf(lo, av);
      unsigned b = (unsigned)d >> bsh;
      unsigned pos = base[b] + atomicAdd(&h[b], 1u);
      if (full)
        cbuf64[pos] = ((unsigned long long)(((((unsigned)d) & lmask) << 24) | (unsigned)s) << 32)
                      | ((mk << 24) | (unsigned)(e0 + j));
      else
        cbuf32[pos] = ((((unsigned)d) & lmask) << 24) | (unsigned)(e0 + j);
    }
  }
  for (int e = cbase + n4 * 4 + threadIdx.x; e < cend; e += 256) {
    int d = dst[e], s = src[e];
    float r = rowmax[s];
    unsigned mk = (__float_as_uint(r) >> 31);
    float av = fabsf(r);
    if (mk) hi = fmaxf(hi, av); else lo = fmaxf(lo, av);
    unsigned b = (unsigned)d >> bsh;
    unsigned pos = base[b] + atomicAdd(&h[b], 1u);
    if (full)
      cbuf64[pos] = ((unsigned long long)(((((unsigned)d) & lmask) << 24) | (unsigned)s) << 32)
                    | ((mk << 24) | (unsigned)e);
    else
      cbuf32[pos] = ((((unsigned)d) & lmask) << 24) | (unsigned)e;
  }
  for (int o = 32; o; o >>= 1) { hi = fmaxf(hi, __shfl_xor(hi, o)); lo = fmaxf(lo, __shfl_xor(lo, o)); }
  int wid = threadIdx.x >> 6, lane = threadIdx.x & 63;
  if (lane == 0) { sh_hi[wid] = hi; sh_lo[wid] = lo; }
  __syncthreads();
  if (threadIdx.x == 0) {
    float hh = fmaxf(fmaxf(sh_hi[0], sh_hi[1]), fmaxf(sh_hi[2], sh_hi[3]));
    float ll = fmaxf(fmaxf(sh_lo[0], sh_lo[1]), fmaxf(sh_lo[2], sh_lo[3]));
    atomicMax(&slot_ehi[blockIdx.x & 255], __float_as_uint(hh));
    atomicMax(&slot_elo[blockIdx.x & 255], __float_as_uint(ll));
  }
}

// Reduce 256-slot amax arrays -> scales in head. which=0: msg; which=1: out.
__global__ void k_scales(unsigned* head, const unsigned* shi, const unsigned* slo, int which) {
  __shared__ unsigned smh[256], sml[256];
  int t = threadIdx.x;
  smh[t] = shi[t]; sml[t] = slo[t];
  __syncthreads();
  for (int off = 128; off > 0; off >>= 1) {
    if (t < off) {
      smh[t] = smh[t] > smh[t + off] ? smh[t] : smh[t + off];
      sml[t] = sml[t] > sml[t + off] ? sml[t] : sml[t + off];
    }
    __syncthreads();
  }
  if (t == 0) {
    float* hf = (float*)head;
    float ah = __uint_as_float(smh[0]);
    float al = __uint_as_float(sml[0]);
    hf[6 + which * 2]     = __fdiv_rn(fmaxf(ah, 1e-8f), 127.0f);
    hf[6 + which * 2 + 1] = __fdiv_rn(fmaxf(al, 1e-8f), 7.0f);
  }
}

// MEGA: blocks [0,NB) = finesort (opay ORDERED, meta=(cnt<<32)|start);
//       blocks [NB,..) = quant8.
__global__ void k_mega_fq(const unsigned long long* cbuf64, const unsigned* cbuf32,
                          const unsigned* btot,
                          unsigned long long* opay, unsigned* order32,
                          unsigned long long* meta, unsigned* head,
                          int N, int NB, int bsh, int full,
                          const float* x, signed char* xq8, const unsigned char* msk) {
  __shared__ unsigned h[256], lofs[256], cur[256];
  __shared__ unsigned sb[1024];
  __shared__ unsigned long long srt[FS_CAP];
  int t = threadIdx.x;
  if ((int)blockIdx.x >= NB) {
    int bid = blockIdx.x - NB;
    int w = (bid * 256 + t) >> 6;
    int lane = t & 63;
    if (w >= N) return;
    const float* hf = (const float*)head;
    bool m = msk[w] != 0;
    float sc = m ? hf[6] : hf[7];
    float qm = m ? 127.0f : 7.0f;
    float tv = __fdiv_rn(x[(size_t)w * 64 + lane], sc);
    tv = fminf(fmaxf(tv, -qm), qm);
    tv = rintf(tv);
    xq8[(size_t)w * 64 + lane] = (signed char)tv;
    return;
  }
  int b = blockIdx.x;
  for (int i = t; i < 1024; i += 256) sb[i] = (i < NB) ? btot[i] : 0u;
  __syncthreads();
  for (int off = 1; off < 1024; off <<= 1) {
    unsigned v[4];
    #pragma unroll
    for (int j = 0; j < 4; j++) { int i = t + j * 256; v[j] = (i >= off) ? sb[i - off] : 0u; }
    __syncthreads();
    #pragma unroll
    for (int j = 0; j < 4; j++) { int i = t + j * 256; sb[i] += v[j]; }
    __syncthreads();
  }
  unsigned rbase = (b == 0) ? 0u : sb[b - 1];
  unsigned rend = sb[b];
  unsigned n = rend - rbase;
  h[t] = 0u;
  __syncthreads();
  bool staged = (n <= (unsigned)FS_CAP);
  for (unsigned j = rbase + (unsigned)t; j < rend; j += 256) {
    unsigned loc = full ? (unsigned)(cbuf64[j] >> 56) : (cbuf32[j] >> 24);
    atomicAdd(&h[loc], 1u);
  }
  __syncthreads();
  lofs[t] = h[t];
  __syncthreads();
  for (int off = 1; off < 256; off <<= 1) {
    unsigned v = (t >= off) ? lofs[t - off] : 0u;
    __syncthreads();
    lofs[t] += v;
    __syncthreads();
  }
  unsigned dcount = h[t];
  unsigned excl = lofs[t] - dcount;
  cur[t] = excl;
  int nper = 1 << bsh;
  int node = (b << bsh) + t;
  bool valid = (t < nper) && (node < N);
  if (valid)
    meta[node] = ((unsigned long long)dcount << 32) | (unsigned long long)(rbase + excl);
  __syncthreads();
  if (staged) {
    for (unsigned j = (unsigned)t; j < n; j += 256) {
      unsigned long long v = full ? cbuf64[rbase + j]
                                  : (unsigned long long)cbuf32[rbase + j];
      unsigned loc = full ? (unsigned)(v >> 56) : (((unsigned)v) >> 24);
      srt[atomicAdd(&cur[loc], 1u)] = v;
    }
    __syncthreads();
    if (valid && dcount > 1u) {   // nearly-sorted (chunk order preserved)
      for (unsigned i = 1; i < dcount; i++) {
        unsigned long long key = srt[excl + i];
        unsigned kk = (unsigned)key & 0xFFFFFFu;
        int j = (int)i - 1;
        while (j >= 0 && ((unsigned)srt[excl + j] & 0xFFFFFFu) > kk) {
          srt[excl + j + 1] = srt[excl + j]; j--;
        }
        srt[excl + (unsigned)(j + 1)] = key;
      }
    }
    __syncthreads();
    for (unsigned j = (unsigned)t; j < n; j += 256) {
      if (full) opay[rbase + j] = srt[j];
      else order32[rbase + j] = (unsigned)srt[j] & 0x00FFFFFFu;
    }
  } else {
    for (unsigned j = rbase + (unsigned)t; j < rend; j += 256) {
      if (full) {
        unsigned long long v = cbuf64[j];
        unsigned pos = rbase + atomicAdd(&cur[(unsigned)(v >> 56)], 1u);
        opay[pos] = v;
      } else {
        unsigned v = cbuf32[j];
        unsigned pos = rbase + atomicAdd(&cur[v >> 24], 1u);
        order32[pos] = v & 0x00FFFFFFu;
      }
    }
    __syncthreads();
    if (valid && dcount > 1u) {   // adversarial only
      unsigned s0 = rbase + excl;
      if (full) {
        for (unsigned i = 1; i < dcount; i++) {
          unsigned long long key = opay[s0 + i];
          unsigned kk = (unsigned)key & 0xFFFFFFu;
          int j = (int)i - 1;
          while (j >= 0 && ((unsigned)opay[s0 + j] & 0xFFFFFFu) > kk) {
            opay[s0 + j + 1] = opay[s0 + j]; j--;
          }
          opay[s0 + (unsigned)(j + 1)] = key;
        }
      } else {
        for (unsigned i = 1; i < dcount; i++) {
          unsigned key = order32[s0 + i];
          int j = (int)i - 1;
          while (j >= 0 && order32[s0 + j] > key) { order32[s0 + j + 1] = order32[s0 + j]; j--; }
          order32[s0 + (unsigned)(j + 1)] = key;
        }
      }
    }
  }
}

// Unified aggregation: 16-lane group per node, ANY degree via 16-entry tiles.
// Per tile: lane g holds payload for entry kb+g; 16 u32 gathers in flight;
// in-lane ordered adds (pads reuse slot 0's row with scale 0: +-0, exact).
__global__ void k_aggr_uni(const signed char* xq8,
                           const unsigned long long* opay, const unsigned* order32,
                           const int* src, const unsigned char* msk,
                           const unsigned long long* meta, const unsigned* head,
                           unsigned* slot_ohi, unsigned* slot_olo,
                           float* out, int N, int mode) {
  int t = blockIdx.x * blockDim.x + threadIdx.x;
  int node = t >> 4;
  int g = threadIdx.x & 15;
  if (node >= N) return;
  unsigned long long mm = meta[node];
  unsigned d = (unsigned)(mm >> 32);
  unsigned s0 = (unsigned)mm;
  const float* hf = (const float*)head;
  float shi = hf[6], slo = hf[7];
  int gbase = threadIdx.x & ~15;

  float acc0 = 0.0f, acc1 = 0.0f, acc2 = 0.0f, acc3 = 0.0f;
  for (unsigned kb = 0; kb < d; kb += 16) {
    unsigned pay = 0u;
    if (kb + (unsigned)g < d) {
      if (mode == 2) {
        unsigned long long v = opay[s0 + kb + (unsigned)g];
        pay = ((unsigned)(v >> 32) & 0xFFFFFFu) | (((unsigned)(v >> 24) & 1u) << 31);
      } else {
        unsigned e = order32[s0 + kb + (unsigned)g];
        int s = src[e];
        pay = (unsigned)s | (((unsigned)msk[s]) << 31);
      }
    }
    unsigned rem = d - kb;            // >=1
    unsigned wv[16];
    #pragma unroll
    for (int j = 0; j < 16; j++) {
      int sl = gbase + (((unsigned)j < rem) ? j : 0);
      unsigned p = __shfl(pay, sl);
      wv[j] = *(const unsigned*)(xq8 + (size_t)(p & 0x7FFFFFFFu) * 64 + g * 4);
    }
    #pragma unroll
    for (int j = 0; j < 16; j++) {
      int sl = gbase + (((unsigned)j < rem) ? j : 0);
      unsigned p = __shfl(pay, sl);
      float s = ((unsigned)j < rem) ? ((p >> 31) ? shi : slo) : 0.0f;
      unsigned w = wv[j];
      acc0 = __fadd_rn(acc0, __fmul_rn(s, (float)(int)(signed char)(w & 0xFF)));
      acc1 = __fadd_rn(acc1, __fmul_rn(s, (float)(int)(signed char)((w >> 8) & 0xFF)));
      acc2 = __fadd_rn(acc2, __fmul_rn(s, (float)(int)(signed char)((w >> 16) & 0xFF)));
      acc3 = __fadd_rn(acc3, __fmul_rn(s, (float)(int)(signed char)((w >> 24) & 0xFF)));
    }
  }
  float4 o4; o4.x = acc0; o4.y = acc1; o4.z = acc2; o4.w = acc3;
  *(float4*)(out + (size_t)node * 64 + g * 4) = o4;

  float a = fmaxf(fmaxf(fabsf(acc0), fabsf(acc1)), fmaxf(fabsf(acc2), fabsf(acc3)));
  #pragma unroll
  for (int o = 8; o; o >>= 1) a = fmaxf(a, __shfl_xor(a, o));
  if (g == 0) {
    unsigned* sl = msk[node] ? slot_ohi : slot_olo;
    atomicMax(&sl[node & 255], __float_as_uint(a));
  }
}

// Mode-0 fallback: wave per node, quantize from x on the fly.
__global__ void k_aggr_wave0(const float* x, const unsigned* order32,
                             const int* src, const unsigned char* msk,
                             const unsigned long long* meta, const unsigned* head,
                             unsigned* slot_ohi, unsigned* slot_olo,
                             float* out, int N) {
  int w = (int)((blockIdx.x * blockDim.x + threadIdx.x) >> 6);
  int lane = threadIdx.x & 63;
  if (w >= N) return;
  int node = w;
  unsigned long long mm = meta[node];
  unsigned d = (unsigned)(mm >> 32);
  unsigned s0 = (unsigned)mm;
  const float* hf = (const float*)head;
  float shi = hf[6], slo = hf[7];
  float acc = 0.0f;
  for (unsigned k = 0; k < d; k++) {
    unsigned e = order32[s0 + k];
    unsigned sn = (unsigned)src[e];
    bool m = msk[sn] != 0;
    float sc = m ? shi : slo;
    float qm = m ? 127.0f : 7.0f;
    float tq = __fdiv_rn(x[(size_t)sn * 64 + lane], sc);
    tq = fminf(fmaxf(tq, -qm), qm);
    tq = rintf(tq);
    acc = __fadd_rn(acc, __fmul_rn(sc, tq));
  }
  out[(size_t)node * 64 + lane] = acc;
  float a = fabsf(acc);
  for (int o = 32; o; o >>= 1) a = fmaxf(a, __shfl_xor(a, o));
  if (lane == 0) {
    unsigned* sl = (msk[node] != 0) ? slot_ohi : slot_olo;
    atomicMax(&sl[node & 255], __float_as_uint(a));
  }
}

// Final fake-quant of output rows (in-place, float).
__global__ void k_quant_rows(const float* in, float* out, const unsigned char* msk,
                             const unsigned* head, int N) {
  int w = (int)((blockIdx.x * blockDim.x + threadIdx.x) >> 6);
  int lane = threadIdx.x & 63;
  if (w >= N) return;
  const float* hf = (const float*)head;
  bool m = msk[w] != 0;
  float sc = m ? hf[8] : hf[9];
  float qm = m ? 127.0f : 7.0f;
  float v = in[(size_t)w * 64 + lane];
  float t = __fdiv_rn(v, sc);
  t = fminf(fmaxf(t, -qm), qm);
  t = rintf(t);
  out[(size_t)w * 64 + lane] = __fmul_rn(sc, t);
}

extern "C" void kernel_launch(void* const* d_in, const int* in_sizes, int n_in,
                              void* d_out, int out_size, void* d_ws, size_t ws_size,
                              hipStream_t stream) {
  const float* x = (const float*)d_in[0];
  const int* ei = (const int*)d_in[1];
  const void* mraw = d_in[2];
  int N = in_sizes[2];
  int E = in_sizes[1] / 2;
  const int* src = ei;
  const int* dst = ei + E;
  float* out = (float*)d_out;

  int bsh = 7;
  while ((((N - 1) >> bsh) + 1) > 1024 && bsh < 8) bsh++;
  int NB = ((N - 1) >> bsh) + 1;
  int vec = (((uintptr_t)src & 15) == 0) && (((uintptr_t)dst & 15) == 0);

  int bpchunk = 2048;
  if ((E + bpchunk - 1) / bpchunk > 512)
    bpchunk = (((E + 511) / 512) + 3) & ~3;
  int nbp = (E + bpchunk - 1) / bpchunk;

  char* ws = (char*)d_ws;
  auto al = [](size_t v) { return ((v + 255) / 256) * 256; };
  size_t o_sehi = 256, o_selo = 1280, o_sohi = 2304, o_solo = 3328;
  size_t o_btot = 4352;
  size_t o_M = al(o_btot + (size_t)(NB + 1) * 4);
  size_t o_msk = al(o_M + (size_t)nbp * NB * 4);
  size_t o_rowmax = al(o_msk + (size_t)N);
  size_t o_meta = al(o_rowmax + (size_t)N * 4);
  size_t o_cbuf = al(o_meta + (size_t)N * 8);

  size_t o_opay = al(o_cbuf + (size_t)E * 8);
  size_t o_xq8f = al(o_opay + (size_t)E * 8);
  size_t need_full = o_xq8f + (size_t)N * 64;
  size_t o_order_c = al(o_cbuf + (size_t)E * 4);
  size_t o_xq8c = al(o_order_c + (size_t)E * 4);
  size_t need_compat = o_xq8c + (size_t)N * 64;

  int mode;
  if (ws_size >= need_full && E < (1 << 24) && N < (1 << 24)) mode = 2;
  else if (ws_size >= need_compat && E < (1 << 24)) mode = 1;
  else mode = 0;

  unsigned* head = (unsigned*)ws;
  unsigned* slot_ehi = (unsigned*)(ws + o_sehi);
  unsigned* slot_elo = (unsigned*)(ws + o_selo);
  unsigned* slot_ohi = (unsigned*)(ws + o_sohi);
  unsigned* slot_olo = (unsigned*)(ws + o_solo);
  unsigned* btot = (unsigned*)(ws + o_btot);
  unsigned* M = (unsigned*)(ws + o_M);
  unsigned char* msk = (unsigned char*)(ws + o_msk);
  float* rowmax = (float*)(ws + o_rowmax);
  unsigned long long* meta = (unsigned long long*)(ws + o_meta);
  unsigned long long* cbuf64 = (unsigned long long*)(ws + o_cbuf);
  unsigned* cbuf32 = (unsigned*)(ws + o_cbuf);
  unsigned long long* opay = (unsigned long long*)(ws + o_opay);
  unsigned* order32 = (unsigned*)(ws + o_order_c);
  signed char* xq8 = (signed char*)(ws + ((mode == 2) ? o_xq8f : o_xq8c));

  int rowBlocks = (N + 3) / 4;
  int full = (mode == 2);
  int uniBlocks = (N + 15) / 16;
  int qBlocks = (mode >= 1) ? rowBlocks : 0;

  k_zero<<<8, 256, 0, stream>>>(head, 1088);   // head + 4 slot arrays
  k_detect<<<256, 256, 0, stream>>>((const unsigned char*)mraw, head, N);
  k_mega_hr<<<nbp + rowBlocks, 256, 0, stream>>>(dst, M, E, NB, bsh, vec, bpchunk, nbp,
                                                 x, mraw, head, rowmax, msk, N);
  k_colscan<<<NB, 64, 0, stream>>>(M, btot, nbp, NB);
  k_binplace<<<nbp, 256, 0, stream>>>(src, dst, rowmax, M, btot, cbuf64, cbuf32,
                                      slot_ehi, slot_elo, E, NB, bsh, full, vec, bpchunk);
  k_scales<<<1, 256, 0, stream>>>(head, slot_ehi, slot_elo, 0);
  k_mega_fq<<<NB + qBlocks, 256, 0, stream>>>(cbuf64, cbuf32, btot, opay, order32,
                                              meta, head, N, NB, bsh, full,
                                              x, xq8, msk);
  if (mode >= 1) {
    k_aggr_uni<<<uniBlocks, 256, 0, stream>>>(xq8, opay, order32, src, msk,
                                              meta, head, slot_ohi, slot_olo,
                                              out, N, mode);
  } else {
    k_aggr_wave0<<<rowBlocks, 256, 0, stream>>>(x, order32, src, msk, meta, head,
                                                slot_ohi, slot_olo, out, N);
  }
  k_scales<<<1, 256, 0, stream>>>(head, slot_ohi, slot_olo, 1);
  k_quant_rows<<<rowBlocks, 256, 0, stream>>>(out, out, msk, head, N);
}